// Round 1
// baseline (95.998 us; speedup 1.0000x reference)
//
#include <hip/hip_runtime.h>

// DistortionLoss: per-ray exclusive scan of ws and ws*ts, loss accumulate, global mean.
// One wave (64 lanes) per ray. Stage 1 -> per-block partials in d_ws; Stage 2 -> scalar out.

__global__ __launch_bounds__(256) void distloss_stage1(
    const float* __restrict__ ws,
    const float* __restrict__ deltas,
    const float* __restrict__ ts,
    const int*   __restrict__ rays_a,
    float*       __restrict__ partial)
{
    const int lane  = threadIdx.x & 63;
    const int ray   = (blockIdx.x * blockDim.x + threadIdx.x) >> 6;

    const int start = rays_a[ray * 3 + 1];
    const int count = rays_a[ray * 3 + 2];

    float carry_w  = 0.f;
    float carry_wt = 0.f;
    float loss     = 0.f;

    for (int base = 0; base < count; base += 64) {
        const int i   = base + lane;
        const bool on = (i < count);
        const int g   = start + i;

        const float w = on ? ws[g]     : 0.f;
        const float t = on ? ts[g]     : 0.f;
        const float d = on ? deltas[g] : 0.f;
        const float wt = w * t;

        // inclusive scan across the 64-lane wave
        float sw = w, swt = wt;
        #pragma unroll
        for (int off = 1; off < 64; off <<= 1) {
            const float aw  = __shfl_up(sw,  off);
            const float awt = __shfl_up(swt, off);
            if (lane >= off) { sw += aw; swt += awt; }
        }

        const float Wprev  = carry_w  + (sw  - w);   // exclusive
        const float WTprev = carry_wt + (swt - wt);

        loss += 2.f * w * (t * Wprev - WTprev) + w * w * d * (1.f / 3.f);

        carry_w  += __shfl(sw,  63);
        carry_wt += __shfl(swt, 63);
    }

    // wave reduction
    #pragma unroll
    for (int off = 32; off > 0; off >>= 1) loss += __shfl_xor(loss, off);

    __shared__ float sacc[4];
    if (lane == 0) sacc[threadIdx.x >> 6] = loss;
    __syncthreads();
    if (threadIdx.x == 0)
        partial[blockIdx.x] = (sacc[0] + sacc[1]) + (sacc[2] + sacc[3]);
}

__global__ __launch_bounds__(1024) void distloss_stage2(
    const float* __restrict__ partial,
    float*       __restrict__ out,
    int n, float inv_R)
{
    float s = 0.f;
    for (int i = threadIdx.x; i < n; i += 1024) s += partial[i];

    #pragma unroll
    for (int off = 32; off > 0; off >>= 1) s += __shfl_xor(s, off);

    __shared__ float sacc[16];
    const int lane = threadIdx.x & 63;
    if (lane == 0) sacc[threadIdx.x >> 6] = s;
    __syncthreads();
    if (threadIdx.x == 0) {
        float tot = 0.f;
        #pragma unroll
        for (int k = 0; k < 16; ++k) tot += sacc[k];
        out[0] = tot * inv_R;
    }
}

extern "C" void kernel_launch(void* const* d_in, const int* in_sizes, int n_in,
                              void* d_out, int out_size, void* d_ws, size_t ws_size,
                              hipStream_t stream) {
    const float* ws     = (const float*)d_in[0];
    const float* deltas = (const float*)d_in[1];
    const float* ts     = (const float*)d_in[2];
    const int*   rays_a = (const int*)d_in[3];
    float* out     = (float*)d_out;
    float* partial = (float*)d_ws;

    const int R = in_sizes[3] / 3;          // 65536 rays
    const int blocks = R / 4;               // 4 waves (rays) per 256-thread block

    distloss_stage1<<<blocks, 256, 0, stream>>>(ws, deltas, ts, rays_a, partial);
    distloss_stage2<<<1, 1024, 0, stream>>>(partial, out, blocks, 1.0f / (float)R);
}

// Round 2
// 60.099 us; speedup vs baseline: 1.5973x; 1.5973x over previous
//
#include <hip/hip_runtime.h>

// DistortionLoss: per-ray exclusive scan of ws and ws*ts, loss accumulate, global mean.
// One wave (64 lanes) per ray, 4 consecutive elements per lane -> 256 elems/pass,
// single pass for all real rays (max count ~192). Stage1 -> per-block partials in
// d_ws; Stage2 -> scalar out.

__global__ __launch_bounds__(256) void distloss_stage1(
    const float* __restrict__ ws,
    const float* __restrict__ deltas,
    const float* __restrict__ ts,
    const int*   __restrict__ rays_a,
    float*       __restrict__ partial)
{
    const int lane = threadIdx.x & 63;
    const int ray  = (blockIdx.x * blockDim.x + threadIdx.x) >> 6;

    // wave-uniform ray descriptor -> scalar regs
    const int start = __builtin_amdgcn_readfirstlane(rays_a[ray * 3 + 1]);
    const int count = __builtin_amdgcn_readfirstlane(rays_a[ray * 3 + 2]);

    float loss     = 0.f;
    float carry_w  = 0.f;
    float carry_wt = 0.f;

    for (int base = 0; base < count; base += 256) {   // executes once for real rays
        const int i0 = base + 4 * lane;
        const int g  = start + i0;

        // 12 independent predicated loads, issued upfront
        const float w0 = (i0 + 0 < count) ? ws[g + 0] : 0.f;
        const float w1 = (i0 + 1 < count) ? ws[g + 1] : 0.f;
        const float w2 = (i0 + 2 < count) ? ws[g + 2] : 0.f;
        const float w3 = (i0 + 3 < count) ? ws[g + 3] : 0.f;
        const float t0 = (i0 + 0 < count) ? ts[g + 0] : 0.f;
        const float t1 = (i0 + 1 < count) ? ts[g + 1] : 0.f;
        const float t2 = (i0 + 2 < count) ? ts[g + 2] : 0.f;
        const float t3 = (i0 + 3 < count) ? ts[g + 3] : 0.f;
        const float d0 = (i0 + 0 < count) ? deltas[g + 0] : 0.f;
        const float d1 = (i0 + 1 < count) ? deltas[g + 1] : 0.f;
        const float d2 = (i0 + 2 < count) ? deltas[g + 2] : 0.f;
        const float d3 = (i0 + 3 < count) ? deltas[g + 3] : 0.f;

        const float wt0 = w0 * t0, wt1 = w1 * t1, wt2 = w2 * t2, wt3 = w3 * t3;

        // local inclusive prefix (3 dependent adds each, w and wt interleaved)
        const float pw0 = w0,        pwt0 = wt0;
        const float pw1 = pw0 + w1,  pwt1 = pwt0 + wt1;
        const float pw2 = pw1 + w2,  pwt2 = pwt1 + wt2;
        const float pw3 = pw2 + w3,  pwt3 = pwt2 + wt3;

        // wave inclusive scan of lane totals (two independent 6-step chains)
        float sw = pw3, swt = pwt3;
        #pragma unroll
        for (int off = 1; off < 64; off <<= 1) {
            const float aw  = __shfl_up(sw,  off);
            const float awt = __shfl_up(swt, off);
            if (lane >= off) { sw += aw; swt += awt; }
        }

        // exclusive lane prefix + chunk carry
        const float exw  = carry_w  + (sw  - pw3);
        const float exwt = carry_wt + (swt - pwt3);

        // per-element exclusive prefixes; inactive elems have w=0 -> zero loss
        const float W0 = exw,        WT0 = exwt;
        const float W1 = exw + pw0,  WT1 = exwt + pwt0;
        const float W2 = exw + pw1,  WT2 = exwt + pwt1;
        const float W3 = exw + pw2,  WT3 = exwt + pwt2;

        loss += 2.f * (w0 * (t0 * W0 - WT0) + w1 * (t1 * W1 - WT1)
                     + w2 * (t2 * W2 - WT2) + w3 * (t3 * W3 - WT3))
              + (w0 * w0 * d0 + w1 * w1 * d1 + w2 * w2 * d2 + w3 * w3 * d3) * (1.f / 3.f);

        carry_w  += __shfl(sw,  63);
        carry_wt += __shfl(swt, 63);
    }

    // wave reduction
    #pragma unroll
    for (int off = 32; off > 0; off >>= 1) loss += __shfl_xor(loss, off);

    __shared__ float sacc[4];
    if (lane == 0) sacc[threadIdx.x >> 6] = loss;
    __syncthreads();
    if (threadIdx.x == 0)
        partial[blockIdx.x] = (sacc[0] + sacc[1]) + (sacc[2] + sacc[3]);
}

__global__ __launch_bounds__(1024) void distloss_stage2(
    const float* __restrict__ partial,
    float*       __restrict__ out,
    int n, float inv_R)
{
    float s = 0.f;
    for (int i = threadIdx.x; i < n; i += 1024) s += partial[i];

    #pragma unroll
    for (int off = 32; off > 0; off >>= 1) s += __shfl_xor(s, off);

    __shared__ float sacc[16];
    const int lane = threadIdx.x & 63;
    if (lane == 0) sacc[threadIdx.x >> 6] = s;
    __syncthreads();
    if (threadIdx.x == 0) {
        float tot = 0.f;
        #pragma unroll
        for (int k = 0; k < 16; ++k) tot += sacc[k];
        out[0] = tot * inv_R;
    }
}

extern "C" void kernel_launch(void* const* d_in, const int* in_sizes, int n_in,
                              void* d_out, int out_size, void* d_ws, size_t ws_size,
                              hipStream_t stream) {
    const float* ws     = (const float*)d_in[0];
    const float* deltas = (const float*)d_in[1];
    const float* ts     = (const float*)d_in[2];
    const int*   rays_a = (const int*)d_in[3];
    float* out     = (float*)d_out;
    float* partial = (float*)d_ws;

    const int R = in_sizes[3] / 3;          // 65536 rays
    const int blocks = R / 4;               // 4 waves (rays) per 256-thread block

    distloss_stage1<<<blocks, 256, 0, stream>>>(ws, deltas, ts, rays_a, partial);
    distloss_stage2<<<1, 1024, 0, stream>>>(partial, out, blocks, 1.0f / (float)R);
}

// Round 3
// 51.322 us; speedup vs baseline: 1.8705x; 1.1710x over previous
//
#include <hip/hip_runtime.h>

// DistortionLoss: per-ray exclusive scan of ws and ws*ts, loss accumulate, global mean.
// One wave per ray; aligned float4 loads (abase = start & ~3, window 256 >= 3+192)
// with w-only masking so out-of-window garbage is annihilated by w=0.
// Stage1 -> per-block partials in d_ws; Stage2 -> scalar out.

__global__ __launch_bounds__(256) void distloss_stage1(
    const float* __restrict__ ws,
    const float* __restrict__ deltas,
    const float* __restrict__ ts,
    const int*   __restrict__ rays_a,
    float*       __restrict__ partial,
    int N)
{
    const int lane = threadIdx.x & 63;
    const int ray  = (blockIdx.x * blockDim.x + threadIdx.x) >> 6;

    // wave-uniform ray descriptor -> scalar regs
    const int start = __builtin_amdgcn_readfirstlane(rays_a[ray * 3 + 1]);
    const int count = __builtin_amdgcn_readfirstlane(rays_a[ray * 3 + 2]);

    const int abase = start & ~3;        // 16B-aligned window base
    const int lo    = start - abase;     // 0..3
    const int hi    = lo + count;        // window end (<= 195 for real data)

    float loss     = 0.f;
    float carry_w  = 0.f;
    float carry_wt = 0.f;

    for (int base = 0; base < hi; base += 256) {   // executes once for real rays
        const int i0 = base + 4 * lane;            // window-relative, 16B aligned

        float4 w4 = make_float4(0.f, 0.f, 0.f, 0.f);
        float4 t4 = make_float4(0.f, 0.f, 0.f, 0.f);
        float4 d4 = make_float4(0.f, 0.f, 0.f, 0.f);
        if (abase + i0 < N) {                      // N % 4 == 0 -> 16B load stays in bounds
            w4 = *reinterpret_cast<const float4*>(ws     + abase + i0);
            t4 = *reinterpret_cast<const float4*>(ts     + abase + i0);
            d4 = *reinterpret_cast<const float4*>(deltas + abase + i0);
        }

        // mask w only: every loss/scan term carries a factor of w
        const unsigned uc = (unsigned)count;
        const float w0 = ((unsigned)(i0 + 0 - lo) < uc) ? w4.x : 0.f;
        const float w1 = ((unsigned)(i0 + 1 - lo) < uc) ? w4.y : 0.f;
        const float w2 = ((unsigned)(i0 + 2 - lo) < uc) ? w4.z : 0.f;
        const float w3 = ((unsigned)(i0 + 3 - lo) < uc) ? w4.w : 0.f;

        const float wt0 = w0 * t4.x, wt1 = w1 * t4.y, wt2 = w2 * t4.z, wt3 = w3 * t4.w;

        // local inclusive prefix (w and wt chains interleaved)
        const float pw0 = w0,        pwt0 = wt0;
        const float pw1 = pw0 + w1,  pwt1 = pwt0 + wt1;
        const float pw2 = pw1 + w2,  pwt2 = pwt1 + wt2;
        const float pw3 = pw2 + w3,  pwt3 = pwt2 + wt3;

        // wave inclusive scan of lane totals (two independent 6-step chains)
        float sw = pw3, swt = pwt3;
        #pragma unroll
        for (int off = 1; off < 64; off <<= 1) {
            const float aw  = __shfl_up(sw,  off);
            const float awt = __shfl_up(swt, off);
            if (lane >= off) { sw += aw; swt += awt; }
        }

        // exclusive lane prefix + chunk carry
        const float exw  = carry_w  + (sw  - pw3);
        const float exwt = carry_wt + (swt - pwt3);

        // per-element exclusive prefixes; masked elems have w=0 -> zero contribution
        const float W0 = exw,        WT0 = exwt;
        const float W1 = exw + pw0,  WT1 = exwt + pwt0;
        const float W2 = exw + pw1,  WT2 = exwt + pwt1;
        const float W3 = exw + pw2,  WT3 = exwt + pwt2;

        loss += 2.f * (w0 * (t4.x * W0 - WT0) + w1 * (t4.y * W1 - WT1)
                     + w2 * (t4.z * W2 - WT2) + w3 * (t4.w * W3 - WT3))
              + (w0 * w0 * d4.x + w1 * w1 * d4.y + w2 * w2 * d4.z + w3 * w3 * d4.w) * (1.f / 3.f);

        carry_w  += __shfl(sw,  63);
        carry_wt += __shfl(swt, 63);
    }

    // wave reduction
    #pragma unroll
    for (int off = 32; off > 0; off >>= 1) loss += __shfl_xor(loss, off);

    __shared__ float sacc[4];
    if (lane == 0) sacc[threadIdx.x >> 6] = loss;
    __syncthreads();
    if (threadIdx.x == 0)
        partial[blockIdx.x] = (sacc[0] + sacc[1]) + (sacc[2] + sacc[3]);
}

__global__ __launch_bounds__(1024) void distloss_stage2(
    const float* __restrict__ partial,
    float*       __restrict__ out,
    int n, float inv_R)
{
    float s = 0.f;
    for (int i = threadIdx.x; i < n; i += 1024) s += partial[i];

    #pragma unroll
    for (int off = 32; off > 0; off >>= 1) s += __shfl_xor(s, off);

    __shared__ float sacc[16];
    const int lane = threadIdx.x & 63;
    if (lane == 0) sacc[threadIdx.x >> 6] = s;
    __syncthreads();
    if (threadIdx.x == 0) {
        float tot = 0.f;
        #pragma unroll
        for (int k = 0; k < 16; ++k) tot += sacc[k];
        out[0] = tot * inv_R;
    }
}

extern "C" void kernel_launch(void* const* d_in, const int* in_sizes, int n_in,
                              void* d_out, int out_size, void* d_ws, size_t ws_size,
                              hipStream_t stream) {
    const float* ws     = (const float*)d_in[0];
    const float* deltas = (const float*)d_in[1];
    const float* ts     = (const float*)d_in[2];
    const int*   rays_a = (const int*)d_in[3];
    float* out     = (float*)d_out;
    float* partial = (float*)d_ws;

    const int N = in_sizes[0];              // 8388608 samples
    const int R = in_sizes[3] / 3;          // 65536 rays
    const int blocks = R / 4;               // 4 waves (rays) per 256-thread block

    distloss_stage1<<<blocks, 256, 0, stream>>>(ws, deltas, ts, rays_a, partial, N);
    distloss_stage2<<<1, 1024, 0, stream>>>(partial, out, blocks, 1.0f / (float)R);
}

// Round 4
// 42.342 us; speedup vs baseline: 2.2672x; 1.2121x over previous
//
#include <hip/hip_runtime.h>

// DistortionLoss: per-ray exclusive scan of ws and ws*ts, loss accumulate, global mean.
// TWO rays per wave (one per 32-lane half), 8 elems/lane -> 256-elem window per ray,
// single pass (max hi = 3 + ~193 < 256). 5-step half-wave shuffle scan. Loads
// predicated on the ray window; w-only masking annihilates out-of-ray garbage.
// Stage1 -> per-block partials in d_ws; Stage2 -> scalar out.

__device__ __forceinline__ float ray_loss_chunked(
    const float* __restrict__ ws, const float* __restrict__ deltas,
    const float* __restrict__ ts, int start, int count, int N, int lane)
{
    const int abase = start & ~3;
    const int lo    = start - abase;
    const int hi    = lo + count;
    float loss = 0.f, carry_w = 0.f, carry_wt = 0.f;
    for (int base = 0; base < hi; base += 256) {
        const int i0 = base + 4 * lane;
        float4 w4 = make_float4(0.f,0.f,0.f,0.f), t4 = w4, d4 = w4;
        if (i0 < hi && abase + i0 < N) {
            w4 = *reinterpret_cast<const float4*>(ws     + abase + i0);
            t4 = *reinterpret_cast<const float4*>(ts     + abase + i0);
            d4 = *reinterpret_cast<const float4*>(deltas + abase + i0);
        }
        const unsigned uc = (unsigned)count;
        const float w0 = ((unsigned)(i0 + 0 - lo) < uc) ? w4.x : 0.f;
        const float w1 = ((unsigned)(i0 + 1 - lo) < uc) ? w4.y : 0.f;
        const float w2 = ((unsigned)(i0 + 2 - lo) < uc) ? w4.z : 0.f;
        const float w3 = ((unsigned)(i0 + 3 - lo) < uc) ? w4.w : 0.f;
        const float wt0 = w0*t4.x, wt1 = w1*t4.y, wt2 = w2*t4.z, wt3 = w3*t4.w;
        const float pw0 = w0,       pwt0 = wt0;
        const float pw1 = pw0 + w1, pwt1 = pwt0 + wt1;
        const float pw2 = pw1 + w2, pwt2 = pwt1 + wt2;
        const float pw3 = pw2 + w3, pwt3 = pwt2 + wt3;
        float sw = pw3, swt = pwt3;
        #pragma unroll
        for (int off = 1; off < 64; off <<= 1) {
            const float aw  = __shfl_up(sw,  off);
            const float awt = __shfl_up(swt, off);
            if (lane >= off) { sw += aw; swt += awt; }
        }
        const float exw  = carry_w  + (sw  - pw3);
        const float exwt = carry_wt + (swt - pwt3);
        const float W0 = exw,       WT0 = exwt;
        const float W1 = exw + pw0, WT1 = exwt + pwt0;
        const float W2 = exw + pw1, WT2 = exwt + pwt1;
        const float W3 = exw + pw2, WT3 = exwt + pwt2;
        loss += 2.f * (w0*(t4.x*W0 - WT0) + w1*(t4.y*W1 - WT1)
                     + w2*(t4.z*W2 - WT2) + w3*(t4.w*W3 - WT3))
              + (w0*w0*d4.x + w1*w1*d4.y + w2*w2*d4.z + w3*w3*d4.w) * (1.f/3.f);
        carry_w  += __shfl(sw,  63);
        carry_wt += __shfl(swt, 63);
    }
    return loss;
}

__global__ __launch_bounds__(256) void distloss_stage1(
    const float* __restrict__ ws,
    const float* __restrict__ deltas,
    const float* __restrict__ ts,
    const int*   __restrict__ rays_a,
    float*       __restrict__ partial,
    int N)
{
    const int lane = threadIdx.x & 63;
    const int li   = lane & 31;                      // index within half-wave
    const int wid  = (blockIdx.x * blockDim.x + threadIdx.x) >> 6;
    const int ray  = 2 * wid + (lane >> 5);          // half-wave -> ray

    const int start = rays_a[ray * 3 + 1];
    const int count = rays_a[ray * 3 + 2];
    const int abase = start & ~3;                    // 16B-aligned window base
    const int lo    = start - abase;                 // 0..3
    const int hi    = lo + count;                    // window extent

    float loss = 0.f;

    if (!__any(hi > 256)) {
        // ---- fast path: whole ray in one 256-elem window per half-wave ----
        const int i0 = 8 * li;
        const int g  = abase + i0;
        float4 z = make_float4(0.f,0.f,0.f,0.f);
        float4 wa = z, ta = z, da = z, wb = z, tb = z, db = z;
        if (i0 < hi) {                               // covers elems i0..i0+3
            wa = *reinterpret_cast<const float4*>(ws     + g);
            ta = *reinterpret_cast<const float4*>(ts     + g);
            da = *reinterpret_cast<const float4*>(deltas + g);
        }
        if (i0 + 4 < hi) {                           // covers elems i0+4..i0+7
            wb = *reinterpret_cast<const float4*>(ws     + g + 4);
            tb = *reinterpret_cast<const float4*>(ts     + g + 4);
            db = *reinterpret_cast<const float4*>(deltas + g + 4);
        }

        float w[8] = {wa.x, wa.y, wa.z, wa.w, wb.x, wb.y, wb.z, wb.w};
        float t[8] = {ta.x, ta.y, ta.z, ta.w, tb.x, tb.y, tb.z, tb.w};
        float d[8] = {da.x, da.y, da.z, da.w, db.x, db.y, db.z, db.w};

        const unsigned uc = (unsigned)count;
        #pragma unroll
        for (int k = 0; k < 8; ++k)
            if (!((unsigned)(i0 + k - lo) < uc)) w[k] = 0.f;

        // local inclusive prefix over 8 elems (two interleaved chains)
        float pw[8], pt[8];
        pw[0] = w[0]; pt[0] = w[0] * t[0];
        #pragma unroll
        for (int k = 1; k < 8; ++k) {
            pw[k] = pw[k-1] + w[k];
            pt[k] = pt[k-1] + w[k] * t[k];
        }

        // 5-step inclusive scan across the 32-lane half-wave
        float swv = pw[7], stv = pt[7];
        #pragma unroll
        for (int off = 1; off < 32; off <<= 1) {
            const float aw = __shfl_up(swv, off);
            const float at = __shfl_up(stv, off);
            if (li >= off) { swv += aw; stv += at; }
        }
        const float ex  = swv - pw[7];               // exclusive lane prefix
        const float ext = stv - pt[7];

        float acc = 0.f;
        #pragma unroll
        for (int k = 0; k < 8; ++k) {
            const float W  = ex  + (k ? pw[k-1] : 0.f);
            const float WT = ext + (k ? pt[k-1] : 0.f);
            acc += 2.f * w[k] * (t[k] * W - WT) + w[k] * w[k] * d[k] * (1.f/3.f);
        }
        loss = acc;
    } else {
        // ---- rare fallback: full-wave chunked scan, one ray at a time ----
        const int sA = __shfl(start, 0),  cA = __shfl(count, 0);
        const int sB = __shfl(start, 32), cB = __shfl(count, 32);
        loss  = ray_loss_chunked(ws, deltas, ts, sA, cA, N, lane);
        loss += ray_loss_chunked(ws, deltas, ts, sB, cB, N, lane);
    }

    // wave reduction (sums both half-wave rays)
    #pragma unroll
    for (int off = 32; off > 0; off >>= 1) loss += __shfl_xor(loss, off);

    __shared__ float sacc[4];
    if (lane == 0) sacc[threadIdx.x >> 6] = loss;
    __syncthreads();
    if (threadIdx.x == 0)
        partial[blockIdx.x] = (sacc[0] + sacc[1]) + (sacc[2] + sacc[3]);
}

__global__ __launch_bounds__(1024) void distloss_stage2(
    const float* __restrict__ partial,
    float*       __restrict__ out,
    int n, float inv_R)
{
    float s = 0.f;
    for (int i = threadIdx.x; i < n; i += 1024) s += partial[i];

    #pragma unroll
    for (int off = 32; off > 0; off >>= 1) s += __shfl_xor(s, off);

    __shared__ float sacc[16];
    const int lane = threadIdx.x & 63;
    if (lane == 0) sacc[threadIdx.x >> 6] = s;
    __syncthreads();
    if (threadIdx.x == 0) {
        float tot = 0.f;
        #pragma unroll
        for (int k = 0; k < 16; ++k) tot += sacc[k];
        out[0] = tot * inv_R;
    }
}

extern "C" void kernel_launch(void* const* d_in, const int* in_sizes, int n_in,
                              void* d_out, int out_size, void* d_ws, size_t ws_size,
                              hipStream_t stream) {
    const float* ws     = (const float*)d_in[0];
    const float* deltas = (const float*)d_in[1];
    const float* ts     = (const float*)d_in[2];
    const int*   rays_a = (const int*)d_in[3];
    float* out     = (float*)d_out;
    float* partial = (float*)d_ws;

    const int N = in_sizes[0];              // 8388608 samples
    const int R = in_sizes[3] / 3;          // 65536 rays
    const int blocks = R / 8;               // 2 rays/wave, 4 waves/block

    distloss_stage1<<<blocks, 256, 0, stream>>>(ws, deltas, ts, rays_a, partial, N);
    distloss_stage2<<<1, 1024, 0, stream>>>(partial, out, blocks, 1.0f / (float)R);
}